// Round 1
// baseline (1356.248 us; speedup 1.0000x reference)
//
#include <hip/hip_runtime.h>

#define NNODES 50000
#define NEDGES 800000

static inline size_t align_up(size_t x, size_t a){ return (x + a - 1) & ~(a - 1); }

__global__ void k_hist(const int* __restrict__ dst, int* __restrict__ deg, int e){
  int i = blockIdx.x * blockDim.x + threadIdx.x;
  if (i < e) atomicAdd(&deg[dst[i]], 1);
}

// single-block exclusive scan over n ints -> row_ptr[0..n], cursor[i]=row_ptr[i]
__global__ void k_scan(const int* __restrict__ deg, int* __restrict__ row_ptr,
                       int* __restrict__ cursor, int n){
  __shared__ int sdata[1024];
  __shared__ int carry_s;
  int tid = threadIdx.x;
  if (tid == 0) carry_s = 0;
  __syncthreads();
  for (int base = 0; base < n; base += 1024){
    int i = base + tid;
    int v = (i < n) ? deg[i] : 0;
    sdata[tid] = v;
    __syncthreads();
    for (int off = 1; off < 1024; off <<= 1){
      int t = (tid >= off) ? sdata[tid - off] : 0;
      __syncthreads();
      sdata[tid] += t;
      __syncthreads();
    }
    int incl = sdata[tid];
    int carry = carry_s;
    if (i < n){ row_ptr[i] = carry + incl - v; cursor[i] = carry + incl - v; }
    __syncthreads();
    if (tid == 1023) carry_s = carry + incl;
    __syncthreads();
  }
  if (tid == 0) row_ptr[n] = carry_s;
}

__global__ void k_fill(const int* __restrict__ src, const int* __restrict__ dst,
                       int* __restrict__ cursor, int* __restrict__ csr, int e){
  int i = blockIdx.x * blockDim.x + threadIdx.x;
  if (i < e){
    int p = atomicAdd(&cursor[dst[i]], 1);
    csr[p] = src[i];
  }
}

// mean over in-neighbors: agg[i][f] = (1/deg_i) * sum_{j in N_in(i)} h[j][f]
__global__ void __launch_bounds__(256) k_agg(const float* __restrict__ h,
                      const int* __restrict__ row_ptr,
                      const int* __restrict__ csr,
                      float* __restrict__ agg, int n){
  int node = blockIdx.x;
  int f = threadIdx.x;
  int start = row_ptr[node], end = row_ptr[node + 1];
  float acc = 0.f;
  for (int e = start; e < end; ++e){
    int j = csr[e];
    acc += h[(size_t)j * 256 + f];
  }
  int d = end - start;
  float inv = d > 0 ? 1.0f / (float)d : 0.f;
  agg[(size_t)node * 256 + f] = acc * inv;
}

// out[i][:] = relu?( [H[i]|AGG[i]] @ [Ws|Wn]^T + b ); BM=64 rows/block, full BN cols
template<int BN, int RELU>
__global__ void __launch_bounds__(256) k_gemm(const float* __restrict__ H,
       const float* __restrict__ AGG,
       const float* __restrict__ Ws, const float* __restrict__ Wn,
       const float* __restrict__ bias, float* __restrict__ out, int n){
  const int THN = BN / 16;                 // cols per thread (16 or 8)
  __shared__ float As[16][68];             // [kk][row], 272B row stride (16B aligned)
  __shared__ float Bs[16][BN + 4];         // [kk][col]
  int tid = threadIdx.x;
  int tx = tid & 15, ty = tid >> 4;
  int m0 = blockIdx.x * 64;
  float acc[4][THN];
  #pragma unroll
  for (int r = 0; r < 4; ++r)
    #pragma unroll
    for (int c = 0; c < THN; ++c) acc[r][c] = 0.f;

  int arow = tid >> 2;          // 0..63
  int akk  = (tid & 3) * 4;     // 0,4,8,12

  for (int k0 = 0; k0 < 512; k0 += 16){
    const float* Asrc = (k0 < 256) ? H : AGG;
    const float* W    = (k0 < 256) ? Ws : Wn;
    int kbase = k0 & 255;
    // A tile: 64 rows x 16 k
    {
      int row = m0 + arow;
      float4 av = make_float4(0.f, 0.f, 0.f, 0.f);
      if (row < n)
        av = *reinterpret_cast<const float4*>(&Asrc[(size_t)row * 256 + kbase + akk]);
      As[akk + 0][arow] = av.x;
      As[akk + 1][arow] = av.y;
      As[akk + 2][arow] = av.z;
      As[akk + 3][arow] = av.w;
    }
    // B tile: BN rows (output cols) x 16 k, from weight [dout][256] row-major
    if (BN == 256){
      int brow = tid;
      #pragma unroll
      for (int q = 0; q < 4; ++q){
        float4 bv = *reinterpret_cast<const float4*>(&W[(size_t)brow * 256 + kbase + q * 4]);
        Bs[q * 4 + 0][brow] = bv.x;
        Bs[q * 4 + 1][brow] = bv.y;
        Bs[q * 4 + 2][brow] = bv.z;
        Bs[q * 4 + 3][brow] = bv.w;
      }
    } else { // BN == 128
      int brow = tid >> 1;
      int kq = (tid & 1) * 8;
      #pragma unroll
      for (int q = 0; q < 2; ++q){
        float4 bv = *reinterpret_cast<const float4*>(&W[(size_t)brow * 256 + kbase + kq + q * 4]);
        Bs[kq + q * 4 + 0][brow] = bv.x;
        Bs[kq + q * 4 + 1][brow] = bv.y;
        Bs[kq + q * 4 + 2][brow] = bv.z;
        Bs[kq + q * 4 + 3][brow] = bv.w;
      }
    }
    __syncthreads();
    #pragma unroll
    for (int kk = 0; kk < 16; ++kk){
      float4 a4 = *reinterpret_cast<const float4*>(&As[kk][ty * 4]);
      float av[4] = {a4.x, a4.y, a4.z, a4.w};
      #pragma unroll
      for (int cb = 0; cb < THN / 4; ++cb){
        float4 b4 = *reinterpret_cast<const float4*>(&Bs[kk][tx * THN + cb * 4]);
        float bv[4] = {b4.x, b4.y, b4.z, b4.w};
        #pragma unroll
        for (int r = 0; r < 4; ++r)
          #pragma unroll
          for (int c = 0; c < 4; ++c)
            acc[r][cb * 4 + c] += av[r] * bv[c];
      }
    }
    __syncthreads();
  }
  // epilogue: bias + optional relu, float4 stores
  #pragma unroll
  for (int r = 0; r < 4; ++r){
    int row = m0 + ty * 4 + r;
    if (row < n){
      #pragma unroll
      for (int cb = 0; cb < THN / 4; ++cb){
        int col = tx * THN + cb * 4;
        float4 v;
        float* vp = reinterpret_cast<float*>(&v);
        #pragma unroll
        for (int c = 0; c < 4; ++c){
          float x = acc[r][cb * 4 + c] + bias[col + c];
          if (RELU) x = fmaxf(x, 0.f);
          vp[c] = x;
        }
        *reinterpret_cast<float4*>(&out[(size_t)row * BN + col]) = v;
      }
    }
  }
}

extern "C" void kernel_launch(void* const* d_in, const int* in_sizes, int n_in,
                              void* d_out, int out_size, void* d_ws, size_t ws_size,
                              hipStream_t stream){
  const float* x   = (const float*)d_in[0];
  const int*   src = (const int*)d_in[1];
  const int*   dst = (const int*)d_in[2];
  const float* Ws0 = (const float*)d_in[3];
  const float* Wn0 = (const float*)d_in[4];
  const float* b0  = (const float*)d_in[5];
  const float* Ws1 = (const float*)d_in[6];
  const float* Wn1 = (const float*)d_in[7];
  const float* b1  = (const float*)d_in[8];
  const float* Ws2 = (const float*)d_in[9];
  const float* Wn2 = (const float*)d_in[10];
  const float* b2  = (const float*)d_in[11];
  float* out = (float*)d_out;

  char* ws = (char*)d_ws;
  size_t off = 0;
  int* deg     = (int*)(ws + off); off = align_up(off + (size_t)NNODES * 4, 256);
  int* row_ptr = (int*)(ws + off); off = align_up(off + (size_t)(NNODES + 1) * 4, 256);
  int* cursor  = (int*)(ws + off); off = align_up(off + (size_t)NNODES * 4, 256);
  int* csr     = (int*)(ws + off); off = align_up(off + (size_t)NEDGES * 4, 256);
  float* agg   = (float*)(ws + off); off = align_up(off + (size_t)NNODES * 256 * 4, 256);
  float* hbuf  = (float*)(ws + off); off = align_up(off + (size_t)NNODES * 256 * 4, 256);
  (void)ws_size; (void)in_sizes; (void)n_in; (void)out_size;

  // --- build CSR (dst-grouped src lists) once per call ---
  hipMemsetAsync(deg, 0, (size_t)NNODES * 4, stream);
  k_hist<<<(NEDGES + 255) / 256, 256, 0, stream>>>(dst, deg, NEDGES);
  k_scan<<<1, 1024, 0, stream>>>(deg, row_ptr, cursor, NNODES);
  k_fill<<<(NEDGES + 255) / 256, 256, 0, stream>>>(src, dst, cursor, csr, NEDGES);

  int gm = (NNODES + 63) / 64;
  // layer 0: x (N x 256) -> hbuf (N x 256)
  k_agg<<<NNODES, 256, 0, stream>>>(x, row_ptr, csr, agg, NNODES);
  k_gemm<256, 1><<<gm, 256, 0, stream>>>(x, agg, Ws0, Wn0, b0, hbuf, NNODES);
  // layer 1: hbuf -> hbuf (in-place safe: block writes only its own rows, after all reads)
  k_agg<<<NNODES, 256, 0, stream>>>(hbuf, row_ptr, csr, agg, NNODES);
  k_gemm<256, 1><<<gm, 256, 0, stream>>>(hbuf, agg, Ws1, Wn1, b1, hbuf, NNODES);
  // layer 2: hbuf -> out (N x 128), no relu
  k_agg<<<NNODES, 256, 0, stream>>>(hbuf, row_ptr, csr, agg, NNODES);
  k_gemm<128, 0><<<gm, 256, 0, stream>>>(hbuf, agg, Ws2, Wn2, b2, out, NNODES);
}

// Round 2
// 575.200 us; speedup vs baseline: 2.3579x; 2.3579x over previous
//
#include <hip/hip_runtime.h>
#include <stdint.h>

#define NNODES 50000
#define NEDGES 800000

typedef _Float16 f16;
typedef _Float16 f16x2 __attribute__((ext_vector_type(2)));
typedef _Float16 f16x4 __attribute__((ext_vector_type(4)));
typedef _Float16 f16x8 __attribute__((ext_vector_type(8)));
typedef float f32x4 __attribute__((ext_vector_type(4)));

static inline size_t align_up(size_t x, size_t a){ return (x + a - 1) & ~(a - 1); }

__device__ __forceinline__ void gll16(const void* g, void* l){
  __builtin_amdgcn_global_load_lds((const __attribute__((address_space(1))) uint32_t*)(g),
                                   (__attribute__((address_space(3))) uint32_t*)(l), 16, 0, 0);
}

// ---------------- CSR build ----------------
__global__ void k_hist(const int* __restrict__ dst, int* __restrict__ deg, int e){
  int i = blockIdx.x * blockDim.x + threadIdx.x;
  if (i < e) atomicAdd(&deg[dst[i]], 1);
}

__global__ void k_scan(const int* __restrict__ deg, int* __restrict__ row_ptr,
                       int* __restrict__ cursor, int n){
  __shared__ int sdata[1024];
  __shared__ int carry_s;
  int tid = threadIdx.x;
  if (tid == 0) carry_s = 0;
  __syncthreads();
  for (int base = 0; base < n; base += 1024){
    int i = base + tid;
    int v = (i < n) ? deg[i] : 0;
    sdata[tid] = v;
    __syncthreads();
    for (int off = 1; off < 1024; off <<= 1){
      int t = (tid >= off) ? sdata[tid - off] : 0;
      __syncthreads();
      sdata[tid] += t;
      __syncthreads();
    }
    int incl = sdata[tid];
    int carry = carry_s;
    if (i < n){ row_ptr[i] = carry + incl - v; cursor[i] = carry + incl - v; }
    __syncthreads();
    if (tid == 1023) carry_s = carry + incl;
    __syncthreads();
  }
  if (tid == 0) row_ptr[n] = carry_s;
}

__global__ void k_fill(const int* __restrict__ src, const int* __restrict__ dst,
                       int* __restrict__ cursor, int* __restrict__ csr, int e){
  int i = blockIdx.x * blockDim.x + threadIdx.x;
  if (i < e){
    int p = atomicAdd(&cursor[dst[i]], 1);
    csr[p] = src[i];
  }
}

// ---------------- fp32 -> fp16 converts ----------------
__global__ void k_cvtx(const float* __restrict__ in, f16* __restrict__ out, int n4){
  int i = blockIdx.x * blockDim.x + threadIdx.x;
  if (i < n4){
    float4 v = *reinterpret_cast<const float4*>(&in[i * 4]);
    f16x4 o = { (f16)v.x, (f16)v.y, (f16)v.z, (f16)v.w };
    *reinterpret_cast<f16x4*>(&out[i * 4]) = o;
  }
}

__global__ void k_cvtw(const float* a0, const float* a1, const float* a2,
                       const float* a3, const float* a4, const float* a5,
                       f16* o0, f16* o1, f16* o2, f16* o3, f16* o4, f16* o5){
  int seg = blockIdx.y;
  const float* in; f16* out; int n;
  switch (seg){
    case 0: in = a0; out = o0; n = 65536; break;
    case 1: in = a1; out = o1; n = 65536; break;
    case 2: in = a2; out = o2; n = 65536; break;
    case 3: in = a3; out = o3; n = 65536; break;
    case 4: in = a4; out = o4; n = 32768; break;
    default: in = a5; out = o5; n = 32768; break;
  }
  int i = (blockIdx.x * blockDim.x + threadIdx.x) * 4;
  if (i < n){
    float4 v = *reinterpret_cast<const float4*>(&in[i]);
    f16x4 o = { (f16)v.x, (f16)v.y, (f16)v.z, (f16)v.w };
    *reinterpret_cast<f16x4*>(&out[i]) = o;
  }
}

// ---------------- mean aggregation (fp16 in, fp32 acc, fp16 out) ----------------
__global__ void __launch_bounds__(128) k_agg16(const f16* __restrict__ h,
                        const int* __restrict__ row_ptr,
                        const int* __restrict__ csr,
                        f16* __restrict__ agg){
  int node = blockIdx.x;
  int f2 = threadIdx.x;                 // feature pair 0..127
  int s = row_ptr[node], e = row_ptr[node + 1];
  float ax = 0.f, ay = 0.f;
  for (int p = s; p < e; ++p){
    int j = csr[p];
    f16x2 v = *reinterpret_cast<const f16x2*>(&h[(size_t)j * 256 + f2 * 2]);
    ax += (float)v.x; ay += (float)v.y;
  }
  float inv = (e > s) ? 1.f / (float)(e - s) : 0.f;
  f16x2 o = { (f16)(ax * inv), (f16)(ay * inv) };
  *reinterpret_cast<f16x2*>(&agg[(size_t)node * 256 + f2 * 2]) = o;
}

// ---------------- MFMA GEMM: out = relu?( [A0|A1] @ [B0|B1]^T + bias ) ----------------
// A0/A1: [M][256] f16 planes. B0/B1: [N][256] f16 (row-major weights).
// Tile 128x128, BK=64, 4 waves (2x2), mfma_f32_16x16x32_f16.
// LDS: linear [128 rows][128 bytes] per tile; global source pre-swizzled with
// byte_col ^= ((row&7)<<4); ds_read_b128 applies the same XOR -> 2-way (free).
template<int RELU, int OUT16>
__global__ void __launch_bounds__(256) k_mm(const f16* __restrict__ A0, const f16* __restrict__ A1,
                                            const f16* __restrict__ B0, const f16* __restrict__ B1,
                                            const float* __restrict__ bias, void* __restrict__ outp,
                                            int M, int N){
  __shared__ __align__(16) char sA[16384];
  __shared__ __align__(16) char sB[16384];
  int tid = threadIdx.x;
  int lane = tid & 63, wid = tid >> 6;
  int m0 = blockIdx.x * 128;
  int n0 = blockIdx.y * 128;
  int wm = (wid & 1) * 64, wn = (wid >> 1) * 64;

  f32x4 acc[4][4];
  #pragma unroll
  for (int m = 0; m < 4; ++m)
    #pragma unroll
    for (int n = 0; n < 4; ++n)
      acc[m][n] = (f32x4){0.f, 0.f, 0.f, 0.f};

  const int srow = tid >> 3;            // 0..31 (row within 32-row round)
  const int scolx = ((tid & 7) << 4) ^ ((srow & 7) << 4);  // pre-swizzled byte col

  const char* A0b = (const char*)A0;
  const char* A1b = (const char*)A1;
  const char* B0b = (const char*)B0;
  const char* B1b = (const char*)B1;

  for (int kt = 0; kt < 8; ++kt){
    const char* Ab = (kt < 4) ? A0b : A1b;
    const char* Bb = (kt < 4) ? B0b : B1b;
    int kbyte = (kt & 3) * 128;
    if (kt) __syncthreads();
    #pragma unroll
    for (int q = 0; q < 4; ++q){
      int row = q * 32 + srow;
      int ga = m0 + row; if (ga > M - 1) ga = M - 1;
      int gb = n0 + row;                 // always < N (N is 128 or 256, tile <= N)
      gll16(Ab + (size_t)ga * 512 + kbyte + scolx, sA + q * 4096 + wid * 1024);
      gll16(Bb + (size_t)gb * 512 + kbyte + scolx, sB + q * 4096 + wid * 1024);
    }
    __syncthreads();
    #pragma unroll
    for (int kk = 0; kk < 2; ++kk){
      int cb = kk * 64 + ((lane >> 4) << 4);
      f16x8 af[4], bfr[4];
      #pragma unroll
      for (int m = 0; m < 4; ++m){
        int r = wm + m * 16 + (lane & 15);
        af[m] = *reinterpret_cast<const f16x8*>(sA + r * 128 + (cb ^ ((r & 7) << 4)));
      }
      #pragma unroll
      for (int n = 0; n < 4; ++n){
        int r = wn + n * 16 + (lane & 15);
        bfr[n] = *reinterpret_cast<const f16x8*>(sB + r * 128 + (cb ^ ((r & 7) << 4)));
      }
      #pragma unroll
      for (int m = 0; m < 4; ++m)
        #pragma unroll
        for (int n = 0; n < 4; ++n)
          acc[m][n] = __builtin_amdgcn_mfma_f32_16x16x32_f16(af[m], bfr[n], acc[m][n], 0, 0, 0);
    }
  }

  // epilogue: bias + relu, split stores; C/D layout col=lane&15, row=(lane>>4)*4+reg
  int cl = lane & 15, rq = lane >> 4;
  #pragma unroll
  for (int n = 0; n < 4; ++n){
    int gc = n0 + wn + n * 16 + cl;
    float bv = bias[gc];
    #pragma unroll
    for (int m = 0; m < 4; ++m){
      int gr0 = m0 + wm + m * 16 + rq * 4;
      #pragma unroll
      for (int j = 0; j < 4; ++j){
        int gr = gr0 + j;
        if (gr < M){
          float x = acc[m][n][j] + bv;
          if (RELU) x = fmaxf(x, 0.f);
          if (OUT16) ((f16*)outp)[(size_t)gr * N + gc] = (f16)x;
          else       ((float*)outp)[(size_t)gr * N + gc] = x;
        }
      }
    }
  }
}

extern "C" void kernel_launch(void* const* d_in, const int* in_sizes, int n_in,
                              void* d_out, int out_size, void* d_ws, size_t ws_size,
                              hipStream_t stream){
  const float* x   = (const float*)d_in[0];
  const int*   src = (const int*)d_in[1];
  const int*   dst = (const int*)d_in[2];
  const float* Ws0 = (const float*)d_in[3];
  const float* Wn0 = (const float*)d_in[4];
  const float* b0  = (const float*)d_in[5];
  const float* Ws1 = (const float*)d_in[6];
  const float* Wn1 = (const float*)d_in[7];
  const float* b1  = (const float*)d_in[8];
  const float* Ws2 = (const float*)d_in[9];
  const float* Wn2 = (const float*)d_in[10];
  const float* b2  = (const float*)d_in[11];
  float* out = (float*)d_out;

  char* ws = (char*)d_ws;
  size_t off = 0;
  int* deg     = (int*)(ws + off); off = align_up(off + (size_t)NNODES * 4, 256);
  int* row_ptr = (int*)(ws + off); off = align_up(off + (size_t)(NNODES + 1) * 4, 256);
  int* cursor  = (int*)(ws + off); off = align_up(off + (size_t)NNODES * 4, 256);
  int* csr     = (int*)(ws + off); off = align_up(off + (size_t)NEDGES * 4, 256);
  f16* xh   = (f16*)(ws + off); off = align_up(off + (size_t)NNODES * 256 * 2, 256);
  f16* aggh = (f16*)(ws + off); off = align_up(off + (size_t)NNODES * 256 * 2, 256);
  f16* hA   = (f16*)(ws + off); off = align_up(off + (size_t)NNODES * 256 * 2, 256);
  f16* hB   = (f16*)(ws + off); off = align_up(off + (size_t)NNODES * 256 * 2, 256);
  f16* w16  = (f16*)(ws + off); off = align_up(off + (size_t)327680 * 2, 256);
  f16* Ws0h = w16;              f16* Wn0h = w16 + 65536;
  f16* Ws1h = w16 + 131072;     f16* Wn1h = w16 + 196608;
  f16* Ws2h = w16 + 262144;     f16* Wn2h = w16 + 294912;
  (void)ws_size; (void)in_sizes; (void)n_in; (void)out_size;

  // CSR build
  hipMemsetAsync(deg, 0, (size_t)NNODES * 4, stream);
  k_hist<<<(NEDGES + 255) / 256, 256, 0, stream>>>(dst, deg, NEDGES);
  k_scan<<<1, 1024, 0, stream>>>(deg, row_ptr, cursor, NNODES);
  k_fill<<<(NEDGES + 255) / 256, 256, 0, stream>>>(src, dst, cursor, csr, NEDGES);

  // converts
  int n4 = NNODES * 256 / 4;
  k_cvtx<<<(n4 + 255) / 256, 256, 0, stream>>>(x, xh, n4);
  k_cvtw<<<dim3(64, 6), 256, 0, stream>>>(Ws0, Wn0, Ws1, Wn1, Ws2, Wn2,
                                          Ws0h, Wn0h, Ws1h, Wn1h, Ws2h, Wn2h);

  int gm = (NNODES + 127) / 128;
  // layer 0
  k_agg16<<<NNODES, 128, 0, stream>>>(xh, row_ptr, csr, aggh);
  k_mm<1, 1><<<dim3(gm, 2), 256, 0, stream>>>(xh, aggh, Ws0h, Wn0h, b0, hA, NNODES, 256);
  // layer 1
  k_agg16<<<NNODES, 128, 0, stream>>>(hA, row_ptr, csr, aggh);
  k_mm<1, 1><<<dim3(gm, 2), 256, 0, stream>>>(hA, aggh, Ws1h, Wn1h, b1, hB, NNODES, 256);
  // layer 2
  k_agg16<<<NNODES, 128, 0, stream>>>(hB, row_ptr, csr, aggh);
  k_mm<0, 0><<<dim3(gm, 1), 256, 0, stream>>>(hB, aggh, Ws2h, Wn2h, b2, out, NNODES, 128);
}

// Round 3
// 383.959 us; speedup vs baseline: 3.5323x; 1.4981x over previous
//
#include <hip/hip_runtime.h>
#include <stdint.h>

#define NNODES 50000
#define NEDGES 800000
#define NB_SCAN ((NNODES + 255) / 256)   // 196

typedef _Float16 f16;
typedef _Float16 f16x2 __attribute__((ext_vector_type(2)));
typedef _Float16 f16x4 __attribute__((ext_vector_type(4)));
typedef _Float16 f16x8 __attribute__((ext_vector_type(8)));
typedef float f32x4 __attribute__((ext_vector_type(4)));

static inline size_t align_up(size_t x, size_t a){ return (x + a - 1) & ~(a - 1); }

__device__ __forceinline__ void gll16(const void* g, void* l){
  __builtin_amdgcn_global_load_lds((const __attribute__((address_space(1))) uint32_t*)(g),
                                   (__attribute__((address_space(3))) uint32_t*)(l), 16, 0, 0);
}

// ---------------- CSR build ----------------
__global__ void k_hist(const int* __restrict__ dst, int* __restrict__ deg, int e){
  int i = blockIdx.x * blockDim.x + threadIdx.x;
  if (i < e) atomicAdd(&deg[dst[i]], 1);
}

// per-block local exclusive scan (256/block) + block sums
__global__ void __launch_bounds__(256) k_scan1(const int* __restrict__ deg,
                        int* __restrict__ row_ptr, int* __restrict__ bsum, int n){
  __shared__ int s[256];
  int tid = threadIdx.x;
  int i = blockIdx.x * 256 + tid;
  int v = (i < n) ? deg[i] : 0;
  s[tid] = v;
  __syncthreads();
  #pragma unroll
  for (int off = 1; off < 256; off <<= 1){
    int t = (tid >= off) ? s[tid - off] : 0;
    __syncthreads();
    s[tid] += t;
    __syncthreads();
  }
  if (i < n) row_ptr[i] = s[tid] - v;       // local exclusive
  if (tid == 255) bsum[blockIdx.x] = s[255];
}

// single small block: exclusive scan of block sums, write total
__global__ void __launch_bounds__(256) k_scan2(const int* __restrict__ bsum,
                        int* __restrict__ boff, int* __restrict__ row_ptr, int nb, int n){
  __shared__ int s[256];
  int tid = threadIdx.x;
  int v = (tid < nb) ? bsum[tid] : 0;
  s[tid] = v;
  __syncthreads();
  #pragma unroll
  for (int off = 1; off < 256; off <<= 1){
    int t = (tid >= off) ? s[tid - off] : 0;
    __syncthreads();
    s[tid] += t;
    __syncthreads();
  }
  if (tid < nb) boff[tid] = s[tid] - v;
  if (tid == 255) row_ptr[n] = s[255];
}

// add block offsets, init cursor
__global__ void __launch_bounds__(256) k_scan3(int* __restrict__ row_ptr,
                        const int* __restrict__ boff, int* __restrict__ cursor, int n){
  int i = blockIdx.x * 256 + threadIdx.x;
  if (i < n){
    int v = row_ptr[i] + boff[blockIdx.x];
    row_ptr[i] = v;
    cursor[i] = v;
  }
}

__global__ void k_fill(const int* __restrict__ src, const int* __restrict__ dst,
                       int* __restrict__ cursor, int* __restrict__ csr, int e){
  int i = blockIdx.x * blockDim.x + threadIdx.x;
  if (i < e){
    int p = atomicAdd(&cursor[dst[i]], 1);
    csr[p] = src[i];
  }
}

// ---------------- fp32 -> fp16 converts ----------------
__global__ void k_cvtx(const float* __restrict__ in, f16* __restrict__ out, int n4){
  int i = blockIdx.x * blockDim.x + threadIdx.x;
  if (i < n4){
    float4 v = *reinterpret_cast<const float4*>(&in[i * 4]);
    f16x4 o = { (f16)v.x, (f16)v.y, (f16)v.z, (f16)v.w };
    *reinterpret_cast<f16x4*>(&out[i * 4]) = o;
  }
}

__global__ void k_cvtw(const float* a0, const float* a1, const float* a2,
                       const float* a3, const float* a4, const float* a5,
                       f16* o0, f16* o1, f16* o2, f16* o3, f16* o4, f16* o5){
  int seg = blockIdx.y;
  const float* in; f16* out; int n;
  switch (seg){
    case 0: in = a0; out = o0; n = 65536; break;
    case 1: in = a1; out = o1; n = 65536; break;
    case 2: in = a2; out = o2; n = 65536; break;
    case 3: in = a3; out = o3; n = 65536; break;
    case 4: in = a4; out = o4; n = 32768; break;
    default: in = a5; out = o5; n = 32768; break;
  }
  int i = (blockIdx.x * blockDim.x + threadIdx.x) * 4;
  if (i < n){
    float4 v = *reinterpret_cast<const float4*>(&in[i]);
    f16x4 o = { (f16)v.x, (f16)v.y, (f16)v.z, (f16)v.w };
    *reinterpret_cast<f16x4*>(&out[i]) = o;
  }
}

// ---------------- mean aggregation ----------------
// one WAVE per node (4 nodes/block); lane owns 4 features (f16x4 = 8B/lane,
// 512B coalesced line per neighbor); 4-deep unroll -> 4 gathers in flight.
__global__ void __launch_bounds__(256) k_agg(const f16* __restrict__ h,
                        const int* __restrict__ row_ptr,
                        const int* __restrict__ csr,
                        f16* __restrict__ agg){
  int wid = threadIdx.x >> 6, lane = threadIdx.x & 63;
  int node = blockIdx.x * 4 + wid;
  if (node >= NNODES) return;
  int s = row_ptr[node], e = row_ptr[node + 1];
  const size_t fo = (size_t)lane * 4;
  f32x4 a0 = {0,0,0,0}, a1 = {0,0,0,0}, a2 = {0,0,0,0}, a3 = {0,0,0,0};
  int p = s;
  for (; p + 4 <= e; p += 4){
    int j0 = csr[p], j1 = csr[p+1], j2 = csr[p+2], j3 = csr[p+3];
    f16x4 v0 = *reinterpret_cast<const f16x4*>(&h[(size_t)j0 * 256 + fo]);
    f16x4 v1 = *reinterpret_cast<const f16x4*>(&h[(size_t)j1 * 256 + fo]);
    f16x4 v2 = *reinterpret_cast<const f16x4*>(&h[(size_t)j2 * 256 + fo]);
    f16x4 v3 = *reinterpret_cast<const f16x4*>(&h[(size_t)j3 * 256 + fo]);
    #pragma unroll
    for (int c = 0; c < 4; ++c){
      a0[c] += (float)v0[c];
      a1[c] += (float)v1[c];
      a2[c] += (float)v2[c];
      a3[c] += (float)v3[c];
    }
  }
  for (; p < e; ++p){
    int j = csr[p];
    f16x4 v = *reinterpret_cast<const f16x4*>(&h[(size_t)j * 256 + fo]);
    #pragma unroll
    for (int c = 0; c < 4; ++c) a0[c] += (float)v[c];
  }
  float inv = (e > s) ? 1.f / (float)(e - s) : 0.f;
  f16x4 o;
  #pragma unroll
  for (int c = 0; c < 4; ++c) o[c] = (f16)((a0[c] + a1[c] + a2[c] + a3[c]) * inv);
  *reinterpret_cast<f16x4*>(&agg[(size_t)node * 256 + fo]) = o;
}

// ---------------- MFMA GEMM: out = relu?( [A0|A1] @ [B0|B1]^T + bias ) ----------------
// A0/A1: [M][256] f16 planes. B0/B1: [N][256] f16 (row-major weights).
// Tile 128x128, BK=64, 4 waves (2x2), mfma_f32_16x16x32_f16.
// LDS: linear [128 rows][128 bytes] per tile; global source pre-swizzled with
// byte_col ^= ((row&7)<<4); ds_read_b128 applies the same XOR -> 2-way (free).
template<int RELU, int OUT16>
__global__ void __launch_bounds__(256) k_mm(const f16* __restrict__ A0, const f16* __restrict__ A1,
                                            const f16* __restrict__ B0, const f16* __restrict__ B1,
                                            const float* __restrict__ bias, void* __restrict__ outp,
                                            int M, int N){
  __shared__ __align__(16) char sA[16384];
  __shared__ __align__(16) char sB[16384];
  int tid = threadIdx.x;
  int lane = tid & 63, wid = tid >> 6;
  int m0 = blockIdx.x * 128;
  int n0 = blockIdx.y * 128;
  int wm = (wid & 1) * 64, wn = (wid >> 1) * 64;

  f32x4 acc[4][4];
  #pragma unroll
  for (int m = 0; m < 4; ++m)
    #pragma unroll
    for (int n = 0; n < 4; ++n)
      acc[m][n] = (f32x4){0.f, 0.f, 0.f, 0.f};

  const int srow = tid >> 3;            // 0..31 (row within 32-row round)
  const int scolx = ((tid & 7) << 4) ^ ((srow & 7) << 4);  // pre-swizzled byte col

  const char* A0b = (const char*)A0;
  const char* A1b = (const char*)A1;
  const char* B0b = (const char*)B0;
  const char* B1b = (const char*)B1;

  for (int kt = 0; kt < 8; ++kt){
    const char* Ab = (kt < 4) ? A0b : A1b;
    const char* Bb = (kt < 4) ? B0b : B1b;
    int kbyte = (kt & 3) * 128;
    if (kt) __syncthreads();
    #pragma unroll
    for (int q = 0; q < 4; ++q){
      int row = q * 32 + srow;
      int ga = m0 + row; if (ga > M - 1) ga = M - 1;
      int gb = n0 + row;                 // always < N (N is 128 or 256, tile <= N)
      gll16(Ab + (size_t)ga * 512 + kbyte + scolx, sA + q * 4096 + wid * 1024);
      gll16(Bb + (size_t)gb * 512 + kbyte + scolx, sB + q * 4096 + wid * 1024);
    }
    __syncthreads();
    #pragma unroll
    for (int kk = 0; kk < 2; ++kk){
      int cb = kk * 64 + ((lane >> 4) << 4);
      f16x8 af[4], bfr[4];
      #pragma unroll
      for (int m = 0; m < 4; ++m){
        int r = wm + m * 16 + (lane & 15);
        af[m] = *reinterpret_cast<const f16x8*>(sA + r * 128 + (cb ^ ((r & 7) << 4)));
      }
      #pragma unroll
      for (int n = 0; n < 4; ++n){
        int r = wn + n * 16 + (lane & 15);
        bfr[n] = *reinterpret_cast<const f16x8*>(sB + r * 128 + (cb ^ ((r & 7) << 4)));
      }
      #pragma unroll
      for (int m = 0; m < 4; ++m)
        #pragma unroll
        for (int n = 0; n < 4; ++n)
          acc[m][n] = __builtin_amdgcn_mfma_f32_16x16x32_f16(af[m], bfr[n], acc[m][n], 0, 0, 0);
    }
  }

  // epilogue: bias + relu, split stores; C/D layout col=lane&15, row=(lane>>4)*4+reg
  int cl = lane & 15, rq = lane >> 4;
  #pragma unroll
  for (int n = 0; n < 4; ++n){
    int gc = n0 + wn + n * 16 + cl;
    float bv = bias[gc];
    #pragma unroll
    for (int m = 0; m < 4; ++m){
      int gr0 = m0 + wm + m * 16 + rq * 4;
      #pragma unroll
      for (int j = 0; j < 4; ++j){
        int gr = gr0 + j;
        if (gr < M){
          float x = acc[m][n][j] + bv;
          if (RELU) x = fmaxf(x, 0.f);
          if (OUT16) ((f16*)outp)[(size_t)gr * N + gc] = (f16)x;
          else       ((float*)outp)[(size_t)gr * N + gc] = x;
        }
      }
    }
  }
}

extern "C" void kernel_launch(void* const* d_in, const int* in_sizes, int n_in,
                              void* d_out, int out_size, void* d_ws, size_t ws_size,
                              hipStream_t stream){
  const float* x   = (const float*)d_in[0];
  const int*   src = (const int*)d_in[1];
  const int*   dst = (const int*)d_in[2];
  const float* Ws0 = (const float*)d_in[3];
  const float* Wn0 = (const float*)d_in[4];
  const float* b0  = (const float*)d_in[5];
  const float* Ws1 = (const float*)d_in[6];
  const float* Wn1 = (const float*)d_in[7];
  const float* b1  = (const float*)d_in[8];
  const float* Ws2 = (const float*)d_in[9];
  const float* Wn2 = (const float*)d_in[10];
  const float* b2  = (const float*)d_in[11];
  float* out = (float*)d_out;

  char* ws = (char*)d_ws;
  size_t off = 0;
  int* deg     = (int*)(ws + off); off = align_up(off + (size_t)NNODES * 4, 256);
  int* row_ptr = (int*)(ws + off); off = align_up(off + (size_t)(NNODES + 1) * 4, 256);
  int* cursor  = (int*)(ws + off); off = align_up(off + (size_t)NNODES * 4, 256);
  int* csr     = (int*)(ws + off); off = align_up(off + (size_t)NEDGES * 4, 256);
  int* bsum    = (int*)(ws + off); off = align_up(off + (size_t)256 * 4, 256);
  int* boff    = (int*)(ws + off); off = align_up(off + (size_t)256 * 4, 256);
  f16* xh   = (f16*)(ws + off); off = align_up(off + (size_t)NNODES * 256 * 2, 256);
  f16* aggh = (f16*)(ws + off); off = align_up(off + (size_t)NNODES * 256 * 2, 256);
  f16* hA   = (f16*)(ws + off); off = align_up(off + (size_t)NNODES * 256 * 2, 256);
  f16* hB   = (f16*)(ws + off); off = align_up(off + (size_t)NNODES * 256 * 2, 256);
  f16* w16  = (f16*)(ws + off); off = align_up(off + (size_t)327680 * 2, 256);
  f16* Ws0h = w16;              f16* Wn0h = w16 + 65536;
  f16* Ws1h = w16 + 131072;     f16* Wn1h = w16 + 196608;
  f16* Ws2h = w16 + 262144;     f16* Wn2h = w16 + 294912;
  (void)ws_size; (void)in_sizes; (void)n_in; (void)out_size;

  // CSR build
  hipMemsetAsync(deg, 0, (size_t)NNODES * 4, stream);
  k_hist<<<(NEDGES + 255) / 256, 256, 0, stream>>>(dst, deg, NEDGES);
  k_scan1<<<NB_SCAN, 256, 0, stream>>>(deg, row_ptr, bsum, NNODES);
  k_scan2<<<1, 256, 0, stream>>>(bsum, boff, row_ptr, NB_SCAN, NNODES);
  k_scan3<<<NB_SCAN, 256, 0, stream>>>(row_ptr, boff, cursor, NNODES);
  k_fill<<<(NEDGES + 255) / 256, 256, 0, stream>>>(src, dst, cursor, csr, NEDGES);

  // converts
  int n4 = NNODES * 256 / 4;
  k_cvtx<<<(n4 + 255) / 256, 256, 0, stream>>>(x, xh, n4);
  k_cvtw<<<dim3(64, 6), 256, 0, stream>>>(Ws0, Wn0, Ws1, Wn1, Ws2, Wn2,
                                          Ws0h, Wn0h, Ws1h, Wn1h, Ws2h, Wn2h);

  int gm = (NNODES + 127) / 128;
  int ga = (NNODES + 3) / 4;
  // layer 0
  k_agg<<<ga, 256, 0, stream>>>(xh, row_ptr, csr, aggh);
  k_mm<1, 1><<<dim3(gm, 2), 256, 0, stream>>>(xh, aggh, Ws0h, Wn0h, b0, hA, NNODES, 256);
  // layer 1
  k_agg<<<ga, 256, 0, stream>>>(hA, row_ptr, csr, aggh);
  k_mm<1, 1><<<dim3(gm, 2), 256, 0, stream>>>(hA, aggh, Ws1h, Wn1h, b1, hB, NNODES, 256);
  // layer 2
  k_agg<<<ga, 256, 0, stream>>>(hB, row_ptr, csr, aggh);
  k_mm<0, 0><<<dim3(gm, 1), 256, 0, stream>>>(hB, aggh, Ws2h, Wn2h, b2, out, NNODES, 128);
}

// Round 4
// 356.859 us; speedup vs baseline: 3.8005x; 1.0759x over previous
//
#include <hip/hip_runtime.h>
#include <stdint.h>

#define NNODES 50000
#define NEDGES 800000
#define NB_SCAN ((NNODES + 255) / 256)   // 196

typedef _Float16 f16;
typedef _Float16 f16x4 __attribute__((ext_vector_type(4)));
typedef _Float16 f16x8 __attribute__((ext_vector_type(8)));
typedef float f32x4 __attribute__((ext_vector_type(4)));
typedef float f32x8 __attribute__((ext_vector_type(8)));

static inline size_t align_up(size_t x, size_t a){ return (x + a - 1) & ~(a - 1); }

__device__ __forceinline__ void gll16(const void* g, void* l){
  __builtin_amdgcn_global_load_lds((const __attribute__((address_space(1))) uint32_t*)(g),
                                   (__attribute__((address_space(3))) uint32_t*)(l), 16, 0, 0);
}

__device__ __forceinline__ f16x8 ld8(const f16* p){ return *reinterpret_cast<const f16x8*>(p); }

// ---------------- CSR build ----------------
__global__ void k_hist(const int* __restrict__ dst, int* __restrict__ deg, int e){
  int i = blockIdx.x * blockDim.x + threadIdx.x;
  if (i < e) atomicAdd(&deg[dst[i]], 1);
}

__global__ void __launch_bounds__(256) k_scan1(const int* __restrict__ deg,
                        int* __restrict__ row_ptr, int* __restrict__ bsum, int n){
  __shared__ int s[256];
  int tid = threadIdx.x;
  int i = blockIdx.x * 256 + tid;
  int v = (i < n) ? deg[i] : 0;
  s[tid] = v;
  __syncthreads();
  #pragma unroll
  for (int off = 1; off < 256; off <<= 1){
    int t = (tid >= off) ? s[tid - off] : 0;
    __syncthreads();
    s[tid] += t;
    __syncthreads();
  }
  if (i < n) row_ptr[i] = s[tid] - v;
  if (tid == 255) bsum[blockIdx.x] = s[255];
}

__global__ void __launch_bounds__(256) k_scan2(const int* __restrict__ bsum,
                        int* __restrict__ boff, int* __restrict__ row_ptr, int nb, int n){
  __shared__ int s[256];
  int tid = threadIdx.x;
  int v = (tid < nb) ? bsum[tid] : 0;
  s[tid] = v;
  __syncthreads();
  #pragma unroll
  for (int off = 1; off < 256; off <<= 1){
    int t = (tid >= off) ? s[tid - off] : 0;
    __syncthreads();
    s[tid] += t;
    __syncthreads();
  }
  if (tid < nb) boff[tid] = s[tid] - v;
  if (tid == 255) row_ptr[n] = s[255];
}

__global__ void __launch_bounds__(256) k_scan3(int* __restrict__ row_ptr,
                        const int* __restrict__ boff, int* __restrict__ cursor, int n){
  int i = blockIdx.x * 256 + threadIdx.x;
  if (i < n){
    int v = row_ptr[i] + boff[blockIdx.x];
    row_ptr[i] = v;
    cursor[i] = v;
  }
}

__global__ void k_fill(const int* __restrict__ src, const int* __restrict__ dst,
                       int* __restrict__ cursor, int* __restrict__ csr, int e){
  int i = blockIdx.x * blockDim.x + threadIdx.x;
  if (i < e){
    int p = atomicAdd(&cursor[dst[i]], 1);
    csr[p] = src[i];
  }
}

// ---------------- fp32 -> fp16 converts ----------------
__global__ void k_cvtx(const float* __restrict__ in, f16* __restrict__ out, int n4){
  int i = blockIdx.x * blockDim.x + threadIdx.x;
  if (i < n4){
    float4 v = *reinterpret_cast<const float4*>(&in[i * 4]);
    f16x4 o = { (f16)v.x, (f16)v.y, (f16)v.z, (f16)v.w };
    *reinterpret_cast<f16x4*>(&out[i * 4]) = o;
  }
}

__global__ void k_cvtw(const float* a0, const float* a1, const float* a2,
                       const float* a3, const float* a4, const float* a5,
                       f16* o0, f16* o1, f16* o2, f16* o3, f16* o4, f16* o5){
  int seg = blockIdx.y;
  const float* in; f16* out; int n;
  switch (seg){
    case 0: in = a0; out = o0; n = 65536; break;
    case 1: in = a1; out = o1; n = 65536; break;
    case 2: in = a2; out = o2; n = 65536; break;
    case 3: in = a3; out = o3; n = 65536; break;
    case 4: in = a4; out = o4; n = 32768; break;
    default: in = a5; out = o5; n = 32768; break;
  }
  int i = (blockIdx.x * blockDim.x + threadIdx.x) * 4;
  if (i < n){
    float4 v = *reinterpret_cast<const float4*>(&in[i]);
    f16x4 o = { (f16)v.x, (f16)v.y, (f16)v.z, (f16)v.w };
    *reinterpret_cast<f16x4*>(&out[i]) = o;
  }
}

// ---------------- MFMA GEMM: C[M][N] = A[M][256] @ Bw[N][256]^T  (all f16, fp32 acc) ----
// Tile 128x128, BK=64, 4 waves (2x2), mfma_f32_16x16x32_f16.
// LDS linear [128 rows][128B]; global source pre-swizzled byte_col ^= ((row&7)<<4);
// ds_read_b128 applies the same XOR -> conflict-free.
__global__ void __launch_bounds__(256) k_mm(const f16* __restrict__ A,
                                            const f16* __restrict__ Bw,
                                            f16* __restrict__ C, int M, int N){
  __shared__ __align__(16) char sA[16384];
  __shared__ __align__(16) char sB[16384];
  int tid = threadIdx.x;
  int lane = tid & 63, wid = tid >> 6;
  int m0 = blockIdx.x * 128;
  int n0 = blockIdx.y * 128;
  int wm = (wid & 1) * 64, wn = (wid >> 1) * 64;

  f32x4 acc[4][4];
  #pragma unroll
  for (int m = 0; m < 4; ++m)
    #pragma unroll
    for (int n = 0; n < 4; ++n)
      acc[m][n] = (f32x4){0.f, 0.f, 0.f, 0.f};

  const int srow = tid >> 3;
  const int scolx = ((tid & 7) << 4) ^ ((srow & 7) << 4);
  const char* Ab = (const char*)A;
  const char* Bb = (const char*)Bw;

  for (int kt = 0; kt < 4; ++kt){
    int kbyte = kt * 128;
    if (kt) __syncthreads();
    #pragma unroll
    for (int q = 0; q < 4; ++q){
      int row = q * 32 + srow;
      int ga = m0 + row; if (ga >= M) ga = M - 1;
      int gb = n0 + row;
      gll16(Ab + (size_t)ga * 512 + kbyte + scolx, sA + q * 4096 + wid * 1024);
      gll16(Bb + (size_t)gb * 512 + kbyte + scolx, sB + q * 4096 + wid * 1024);
    }
    __syncthreads();
    #pragma unroll
    for (int kk = 0; kk < 2; ++kk){
      int cb = kk * 64 + ((lane >> 4) << 4);
      f16x8 af[4], bfr[4];
      #pragma unroll
      for (int m = 0; m < 4; ++m){
        int r = wm + m * 16 + (lane & 15);
        af[m] = *reinterpret_cast<const f16x8*>(sA + r * 128 + (cb ^ ((r & 7) << 4)));
      }
      #pragma unroll
      for (int n = 0; n < 4; ++n){
        int r = wn + n * 16 + (lane & 15);
        bfr[n] = *reinterpret_cast<const f16x8*>(sB + r * 128 + (cb ^ ((r & 7) << 4)));
      }
      #pragma unroll
      for (int m = 0; m < 4; ++m)
        #pragma unroll
        for (int n = 0; n < 4; ++n)
          acc[m][n] = __builtin_amdgcn_mfma_f32_16x16x32_f16(af[m], bfr[n], acc[m][n], 0, 0, 0);
    }
  }

  int cl = lane & 15, rq = lane >> 4;
  #pragma unroll
  for (int n = 0; n < 4; ++n){
    int gc = n0 + wn + n * 16 + cl;
    #pragma unroll
    for (int m = 0; m < 4; ++m){
      int gr0 = m0 + wm + m * 16 + rq * 4;
      #pragma unroll
      for (int j = 0; j < 4; ++j){
        int gr = gr0 + j;
        if (gr < M) C[(size_t)gr * N + gc] = (f16)acc[m][n][j];
      }
    }
  }
}

// ---------------- combine (layers 0/1): h[i] = relu(s[i] + b + mean_j p[j]) ------------
// sp[i] = [s(256) | p(256)] f16, row stride 512. One wave per node; half-wave owns one
// neighbor row (32 lanes x 16B = 512B); unroll 2 -> 4 rows in flight per wave.
__global__ void __launch_bounds__(256) k_comb(const f16* __restrict__ sp,
                        const int* __restrict__ row_ptr,
                        const int* __restrict__ csr,
                        const float* __restrict__ bias,
                        f16* __restrict__ h){
  int wid = threadIdx.x >> 6, lane = threadIdx.x & 63;
  int node = blockIdx.x * 4 + wid;
  if (node >= NNODES) return;
  int s = row_ptr[node], e = row_ptr[node + 1];
  int hh = lane >> 5, fl = lane & 31;
  const f16* pbase = sp + 256 + (size_t)fl * 8;
  f32x8 accA = {0,0,0,0,0,0,0,0}, accB = {0,0,0,0,0,0,0,0};
  int p = s + hh;
  while (p + 2 < e){
    int j0 = csr[p], j1 = csr[p + 2];
    f16x8 v0 = ld8(pbase + (size_t)j0 * 512);
    f16x8 v1 = ld8(pbase + (size_t)j1 * 512);
    #pragma unroll
    for (int c = 0; c < 8; ++c){ accA[c] += (float)v0[c]; accB[c] += (float)v1[c]; }
    p += 4;
  }
  if (p < e){
    int j = csr[p];
    f16x8 v = ld8(pbase + (size_t)j * 512);
    #pragma unroll
    for (int c = 0; c < 8; ++c) accA[c] += (float)v[c];
  }
  #pragma unroll
  for (int c = 0; c < 8; ++c){
    float t = accA[c] + accB[c];
    accA[c] = t + __shfl_xor(t, 32);
  }
  int d = e - s;
  float inv = (d > 0) ? 1.f / (float)d : 0.f;
  if (lane < 32){
    f16x8 sv = ld8(&sp[(size_t)node * 512 + fl * 8]);
    float4 ba = *reinterpret_cast<const float4*>(&bias[fl * 8]);
    float4 bb = *reinterpret_cast<const float4*>(&bias[fl * 8 + 4]);
    float bv[8] = {ba.x, ba.y, ba.z, ba.w, bb.x, bb.y, bb.z, bb.w};
    f16x8 o;
    #pragma unroll
    for (int c = 0; c < 8; ++c){
      float x = (float)sv[c] + bv[c] + accA[c] * inv;
      o[c] = (f16)fmaxf(x, 0.f);
    }
    *reinterpret_cast<f16x8*>(&h[(size_t)node * 256 + fl * 8]) = o;
  }
}

// ---------------- combine (layer 2): out[i] = s[i] + b + mean_j p[j], fp32 ------------
// sp[i] = [s(128) | p(128)] f16, row stride 256. Quarter-wave owns one neighbor row
// (16 lanes x 16B = 256B); 4 rows per load instr; unroll 2 -> 8 rows in flight.
__global__ void __launch_bounds__(256) k_comb2(const f16* __restrict__ sp,
                        const int* __restrict__ row_ptr,
                        const int* __restrict__ csr,
                        const float* __restrict__ bias,
                        float* __restrict__ out){
  int wid = threadIdx.x >> 6, lane = threadIdx.x & 63;
  int node = blockIdx.x * 4 + wid;
  if (node >= NNODES) return;
  int s = row_ptr[node], e = row_ptr[node + 1];
  int hh = lane >> 4, fl = lane & 15;
  const f16* pbase = sp + 128 + (size_t)fl * 8;
  f32x8 accA = {0,0,0,0,0,0,0,0}, accB = {0,0,0,0,0,0,0,0};
  int p = s + hh;
  while (p + 4 < e){
    int j0 = csr[p], j1 = csr[p + 4];
    f16x8 v0 = ld8(pbase + (size_t)j0 * 256);
    f16x8 v1 = ld8(pbase + (size_t)j1 * 256);
    #pragma unroll
    for (int c = 0; c < 8; ++c){ accA[c] += (float)v0[c]; accB[c] += (float)v1[c]; }
    p += 8;
  }
  if (p < e){
    int j = csr[p];
    f16x8 v = ld8(pbase + (size_t)j * 256);
    #pragma unroll
    for (int c = 0; c < 8; ++c) accA[c] += (float)v[c];
  }
  #pragma unroll
  for (int c = 0; c < 8; ++c){
    float t = accA[c] + accB[c];
    t += __shfl_xor(t, 16);
    accA[c] = t + __shfl_xor(t, 32);
  }
  int d = e - s;
  float inv = (d > 0) ? 1.f / (float)d : 0.f;
  if (lane < 16){
    f16x8 sv = ld8(&sp[(size_t)node * 256 + fl * 8]);
    float4 ba = *reinterpret_cast<const float4*>(&bias[fl * 8]);
    float4 bb = *reinterpret_cast<const float4*>(&bias[fl * 8 + 4]);
    float4 o1, o2;
    o1.x = (float)sv[0] + ba.x + accA[0] * inv;
    o1.y = (float)sv[1] + ba.y + accA[1] * inv;
    o1.z = (float)sv[2] + ba.z + accA[2] * inv;
    o1.w = (float)sv[3] + ba.w + accA[3] * inv;
    o2.x = (float)sv[4] + bb.x + accA[4] * inv;
    o2.y = (float)sv[5] + bb.y + accA[5] * inv;
    o2.z = (float)sv[6] + bb.z + accA[6] * inv;
    o2.w = (float)sv[7] + bb.w + accA[7] * inv;
    *reinterpret_cast<float4*>(&out[(size_t)node * 128 + fl * 8]) = o1;
    *reinterpret_cast<float4*>(&out[(size_t)node * 128 + fl * 8 + 4]) = o2;
  }
}

extern "C" void kernel_launch(void* const* d_in, const int* in_sizes, int n_in,
                              void* d_out, int out_size, void* d_ws, size_t ws_size,
                              hipStream_t stream){
  const float* x   = (const float*)d_in[0];
  const int*   src = (const int*)d_in[1];
  const int*   dst = (const int*)d_in[2];
  const float* Ws0 = (const float*)d_in[3];
  const float* Wn0 = (const float*)d_in[4];
  const float* b0  = (const float*)d_in[5];
  const float* Ws1 = (const float*)d_in[6];
  const float* Wn1 = (const float*)d_in[7];
  const float* b1  = (const float*)d_in[8];
  const float* Ws2 = (const float*)d_in[9];
  const float* Wn2 = (const float*)d_in[10];
  const float* b2  = (const float*)d_in[11];
  float* out = (float*)d_out;

  char* ws = (char*)d_ws;
  size_t off = 0;
  int* deg     = (int*)(ws + off); off = align_up(off + (size_t)NNODES * 4, 256);
  int* row_ptr = (int*)(ws + off); off = align_up(off + (size_t)(NNODES + 1) * 4, 256);
  int* cursor  = (int*)(ws + off); off = align_up(off + (size_t)NNODES * 4, 256);
  int* csr     = (int*)(ws + off); off = align_up(off + (size_t)NEDGES * 4, 256);
  int* bsum    = (int*)(ws + off); off = align_up(off + (size_t)256 * 4, 256);
  int* boff    = (int*)(ws + off); off = align_up(off + (size_t)256 * 4, 256);
  f16* xh   = (f16*)(ws + off); off = align_up(off + (size_t)NNODES * 256 * 2, 256);  // also hB
  f16* hA   = (f16*)(ws + off); off = align_up(off + (size_t)NNODES * 256 * 2, 256);
  f16* sp   = (f16*)(ws + off); off = align_up(off + (size_t)NNODES * 512 * 2, 256);
  f16* w16  = (f16*)(ws + off); off = align_up(off + (size_t)327680 * 2, 256);
  f16* Ws0h = w16;              f16* Wn0h = w16 + 65536;   // W0stack [512][256]
  f16* Ws1h = w16 + 131072;     f16* Wn1h = w16 + 196608;  // W1stack [512][256]
  f16* Ws2h = w16 + 262144;     f16* Wn2h = w16 + 294912;  // W2stack [256][256]
  f16* hB = xh;   // xh dead after k_mm layer 0
  (void)ws_size; (void)in_sizes; (void)n_in; (void)out_size;

  // CSR build
  hipMemsetAsync(deg, 0, (size_t)NNODES * 4, stream);
  k_hist<<<(NEDGES + 255) / 256, 256, 0, stream>>>(dst, deg, NEDGES);
  k_scan1<<<NB_SCAN, 256, 0, stream>>>(deg, row_ptr, bsum, NNODES);
  k_scan2<<<1, 256, 0, stream>>>(bsum, boff, row_ptr, NB_SCAN, NNODES);
  k_scan3<<<NB_SCAN, 256, 0, stream>>>(row_ptr, boff, cursor, NNODES);
  k_fill<<<(NEDGES + 255) / 256, 256, 0, stream>>>(src, dst, cursor, csr, NEDGES);

  // converts
  int n4 = NNODES * 256 / 4;
  k_cvtx<<<(n4 + 255) / 256, 256, 0, stream>>>(x, xh, n4);
  k_cvtw<<<dim3(64, 6), 256, 0, stream>>>(Ws0, Wn0, Ws1, Wn1, Ws2, Wn2,
                                          Ws0h, Wn0h, Ws1h, Wn1h, Ws2h, Wn2h);

  int gm = (NNODES + 127) / 128;     // 391
  int gc = (NNODES + 3) / 4;         // 12500
  // layer 0: [s|p] = xh @ W0stack^T ; hA = relu(s + b0 + mean p)
  k_mm<<<dim3(gm, 4), 256, 0, stream>>>(xh, Ws0h, sp, NNODES, 512);
  k_comb<<<gc, 256, 0, stream>>>(sp, row_ptr, csr, b0, hA);
  // layer 1
  k_mm<<<dim3(gm, 4), 256, 0, stream>>>(hA, Ws1h, sp, NNODES, 512);
  k_comb<<<gc, 256, 0, stream>>>(sp, row_ptr, csr, b1, hB);
  // layer 2: [s|p] 256-wide ; out = s + b2 + mean p (fp32)
  k_mm<<<dim3(gm, 2), 256, 0, stream>>>(hB, Ws2h, sp, NNODES, 256);
  k_comb2<<<gc, 256, 0, stream>>>(sp, row_ptr, csr, b2, out);
}